// Round 1
// baseline (34.941 us; speedup 1.0000x reference)
//
#include <hip/hip_runtime.h>

// KA-conv: out[b,o,h,w] = sum_m P_om(v)/ (1+|Q_om(v)|),  v = padded patch value
// m = c*9 + ki*3 + kj, M=144. Pure fp32 VALU workload (~75.5M rational evals).
//
// Layout: block = 256 threads = 64 cols x 4 rowgroups; each thread computes
// 4 consecutive output rows (one column) for ONE output channel o.
// grid = B(4) * O(32) * htiles(4) = 512 blocks.
// o and m are wave-uniform -> coefficient loads should scalarize to s_load.

constexpr int Bn = 4, Cin = 16, Hh = 64, Ww = 64, Oc = 32, Mtot = 144;

__global__ __launch_bounds__(256, 2)
void ka_conv_kernel(const float* __restrict__ x,
                    const float* __restrict__ nums,
                    const float* __restrict__ denoms,
                    float* __restrict__ out) {
  const int tid = threadIdx.x;
  const int w  = tid & 63;        // output column (lane -> coalesced)
  const int rg = tid >> 6;        // rowgroup 0..3
  int blk = blockIdx.x;
  const int ht = blk & 3;  blk >>= 2;   // 4 height tiles of 16 rows
  const int o  = blk & 31; blk >>= 5;   // output channel
  const int b  = blk;                   // batch
  const int h0 = ht * 16 + rg * 4;      // first of this thread's 4 rows

  const float* __restrict__ an = nums   + (size_t)o * Mtot * 6;
  const float* __restrict__ bd = denoms + (size_t)o * Mtot * 4;

  float acc0 = 0.f, acc1 = 0.f, acc2 = 0.f, acc3 = 0.f;

  #pragma unroll 2
  for (int c = 0; c < Cin; ++c) {
    const float* __restrict__ xc = x + (size_t)(b * Cin + c) * (Hh * Ww);
    // Load the 6x3 input patch covering rows h0-1..h0+4, cols w-1..w+1.
    // Clamped address + select-0 keeps loads unconditional & coalesced.
    float X[6][3];
    #pragma unroll
    for (int i = 0; i < 6; ++i) {
      const int  hr  = h0 - 1 + i;
      const int  hc  = min(max(hr, 0), Hh - 1);
      const bool hin = (unsigned)hr < (unsigned)Hh;
      #pragma unroll
      for (int j = 0; j < 3; ++j) {
        const int  wc  = w - 1 + j;
        const int  wcc = min(max(wc, 0), Ww - 1);
        const bool win = (unsigned)wc < (unsigned)Ww;
        const float v  = xc[hc * Ww + wcc];
        X[i][j] = (hin && win) ? v : 0.f;
      }
    }
    #pragma unroll
    for (int ki = 0; ki < 3; ++ki) {
      #pragma unroll
      for (int kj = 0; kj < 3; ++kj) {
        const int m = c * 9 + ki * 3 + kj;
        const float* a  = an + m * 6;   // uniform address -> s_load expected
        const float* bq = bd + m * 4;
        const float a0 = a[0], a1 = a[1], a2 = a[2], a3 = a[3], a4 = a[4], a5 = a[5];
        const float b1 = bq[0], b2 = bq[1], b3 = bq[2], b4 = bq[3];
        #pragma unroll
        for (int p = 0; p < 4; ++p) {
          const float v = X[p + ki][kj];
          // P(v) = a0 + a1 v + ... + a5 v^5  (Horner)
          float num = fmaf(fmaf(fmaf(fmaf(fmaf(a5, v, a4), v, a3), v, a2), v, a1), v, a0);
          // Q(v) = 1 + |b1 v + b2 v^2 + b3 v^3 + b4 v^4|
          float dp  = fmaf(fmaf(fmaf(b4, v, b3), v, b2), v, b1) * v;
          float den = 1.0f + fabsf(dp);
          float r   = __builtin_amdgcn_rcpf(den);  // v_rcp_f32, ~1 ulp
          float t   = num * r;
          if      (p == 0) acc0 += t;
          else if (p == 1) acc1 += t;
          else if (p == 2) acc2 += t;
          else             acc3 += t;
        }
      }
    }
  }

  float* op = out + ((size_t)(b * Oc + o) * Hh + h0) * Ww + w;
  op[0 * Ww] = acc0;
  op[1 * Ww] = acc1;
  op[2 * Ww] = acc2;
  op[3 * Ww] = acc3;
}

extern "C" void kernel_launch(void* const* d_in, const int* in_sizes, int n_in,
                              void* d_out, int out_size, void* d_ws, size_t ws_size,
                              hipStream_t stream) {
  const float* x      = (const float*)d_in[0];
  const float* nums   = (const float*)d_in[1];
  const float* denoms = (const float*)d_in[2];
  float* out          = (float*)d_out;
  // grid encodes (b, o, htile): blockIdx = b*128 + o*4 + ht
  dim3 grid(Bn * Oc * 4);
  ka_conv_kernel<<<grid, 256, 0, stream>>>(x, nums, denoms, out);
}